// Round 5
// baseline (1223.707 us; speedup 1.0000x reference)
//
#include <hip/hip_runtime.h>
#include <cstdint>
#include <cstddef>

typedef __attribute__((ext_vector_type(4))) float    f32x4;
typedef __attribute__((ext_vector_type(4))) float    float4v;
typedef __attribute__((ext_vector_type(8))) _Float16 half8;
typedef __attribute__((ext_vector_type(4))) _Float16 half4;

#define BATCH   16384
#define DIN     2048
#define HID     256
#define NCLS    1000
#define NCLSP   1024
#define NSTEPS  25
#define BETA    0.9f
#define SGK     14.4269504089f   /* 10 * log2(e) */
#define SCL     4096.0f          /* 2^12 lo-scale */
#define ISCL    (1.0f/4096.0f)

// ---- ws layout (bytes); total ~17.8MB ----
#define WS_CUR1   0                       // 16384*256*4 = 16,777,216
#define WS_W2H    16777216                // 1024*256*2  = 524,288
#define WS_W2L    17301504                // 524,288
#define WS_B2P    17825792                // 4096
#define WS_SPARS  17829888                // 4

__device__ __forceinline__ float sigmoid10(float m) {
  // sigmoid(10*(m-1)) = 1/(1+exp2(-10*log2e*(m-1)))
  float z = __builtin_fmaf(-SGK, m, SGK);
  float e = __builtin_amdgcn_exp2f(z);
  return __builtin_amdgcn_rcpf(1.0f + e);
}

// ------------- cast W2/b2 -> f16 hi + scaled-lo (padded to 1024 rows) -------
__global__ void k_cast_w2(const float* __restrict__ W2, const float* __restrict__ b2,
                          _Float16* __restrict__ W2h, _Float16* __restrict__ W2l,
                          float* __restrict__ b2p) {
  int row = blockIdx.x;          // 0..1023
  int t   = threadIdx.x;         // 0..255
  float v = (row < NCLS) ? W2[(size_t)row * HID + t] : 0.0f;
  _Float16 h = (_Float16)v;
  _Float16 l = (_Float16)((v - (float)h) * SCL);
  W2h[(size_t)row * HID + t] = h;
  W2l[(size_t)row * HID + t] = l;
  if (t == 0) b2p[row] = (row < NCLS) ? b2[row] : 0.0f;
}

// ------------- fc1: cur1 = x @ W1^T + b1, f16 2-way split, 3-term MFMA ------
// BM=64, BN=256(all HID), BK=64; 512 thr = 8 waves (2m x 4n), wave tile 32x64
#define ROWB1 144    // 64 f16 (128B) + 16B pad
__global__ __launch_bounds__(512) void k_fc1(
    const float* __restrict__ x, const float* __restrict__ W1,
    const float* __restrict__ b1, float* __restrict__ cur1) {
  extern __shared__ char smem[];
  char* xh = smem;                    // 64*144  = 9216
  char* xl = smem + 9216;             // 9216
  char* wh = smem + 18432;            // 256*144 = 36864
  char* wl = smem + 55296;            // 36864 -> 92160 total
  const int tid = threadIdx.x;
  const int l   = tid & 63;
  const int w   = tid >> 6;
  const int wm  = w >> 2;             // 0..1
  const int wn  = w & 3;              // 0..3
  const int l15 = l & 15, lq = l >> 4;
  const int mbase = blockIdx.x * 64;

  f32x4 am[2][4], ac[2][4];
#pragma unroll
  for (int i = 0; i < 2; ++i)
#pragma unroll
    for (int j = 0; j < 4; ++j) { am[i][j] = f32x4{0,0,0,0}; ac[i][j] = f32x4{0,0,0,0}; }

  const int srow = tid >> 4;          // 0..31
  const int c4   = (tid & 15) * 4;

#pragma unroll 1
  for (int kt = 0; kt < DIN / 64; ++kt) {
    const int k0 = kt * 64;
#pragma unroll
    for (int j = 0; j < 2; ++j) {      // x tile [64][64]
      int r = j * 32 + srow;
      float4v v = *(const float4v*)(x + (size_t)(mbase + r) * DIN + k0 + c4);
      half4 h, lo;
#pragma unroll
      for (int e = 0; e < 4; ++e) {
        _Float16 hv = (_Float16)v[e];
        h[e]  = hv;
        lo[e] = (_Float16)((v[e] - (float)hv) * SCL);
      }
      *(half4*)(xh + r * ROWB1 + (tid & 15) * 8) = h;
      *(half4*)(xl + r * ROWB1 + (tid & 15) * 8) = lo;
    }
#pragma unroll
    for (int j = 0; j < 8; ++j) {      // W1 tile [256][64]
      int r = j * 32 + srow;
      float4v v = *(const float4v*)(W1 + (size_t)r * DIN + k0 + c4);
      half4 h, lo;
#pragma unroll
      for (int e = 0; e < 4; ++e) {
        _Float16 hv = (_Float16)v[e];
        h[e]  = hv;
        lo[e] = (_Float16)((v[e] - (float)hv) * SCL);
      }
      *(half4*)(wh + r * ROWB1 + (tid & 15) * 8) = h;
      *(half4*)(wl + r * ROWB1 + (tid & 15) * 8) = lo;
    }
    __syncthreads();
#pragma unroll
    for (int fk = 0; fk < 2; ++fk) {
      const int g16 = (fk * 4 + lq) * 16;
      half8 ah[2], al[2], bh[4], bl[4];
#pragma unroll
      for (int fm = 0; fm < 2; ++fm) {
        int r = wm * 32 + fm * 16 + l15;
        ah[fm] = *(const half8*)(xh + r * ROWB1 + g16);
        al[fm] = *(const half8*)(xl + r * ROWB1 + g16);
      }
#pragma unroll
      for (int fn = 0; fn < 4; ++fn) {
        int r = wn * 64 + fn * 16 + l15;
        bh[fn] = *(const half8*)(wh + r * ROWB1 + g16);
        bl[fn] = *(const half8*)(wl + r * ROWB1 + g16);
      }
#pragma unroll
      for (int fm = 0; fm < 2; ++fm)
#pragma unroll
        for (int fn = 0; fn < 4; ++fn) {
          am[fm][fn] = __builtin_amdgcn_mfma_f32_16x16x32_f16(ah[fm], bh[fn], am[fm][fn], 0, 0, 0);
          ac[fm][fn] = __builtin_amdgcn_mfma_f32_16x16x32_f16(ah[fm], bl[fn], ac[fm][fn], 0, 0, 0);
          ac[fm][fn] = __builtin_amdgcn_mfma_f32_16x16x32_f16(al[fm], bh[fn], ac[fm][fn], 0, 0, 0);
        }
    }
    __syncthreads();
  }
#pragma unroll
  for (int fn = 0; fn < 4; ++fn) {
    int h = wn * 64 + fn * 16 + l15;
    float b1v = b1[h];
#pragma unroll
    for (int fm = 0; fm < 2; ++fm) {
      int m0 = mbase + wm * 32 + fm * 16 + lq * 4;
#pragma unroll
      for (int e = 0; e < 4; ++e)
        cur1[(size_t)(m0 + e) * HID + h] = am[fm][fn][e] + ac[fm][fn][e] * ISCL + b1v;
    }
  }
}

// ------------- fc2 + both LIF dynamics, spk recomputed in-block -------------
// block: 32 batch rows x 128 classes; 512 thr = 8 waves, all-n (1m x 8n).
// W2 hi/lo frags register-resident; spk1 recurrence in regs -> LDS hi/lo tiles.
#define ROWH 528     // 256 f16 (512B) + 16B pad
__global__ __launch_bounds__(512) void k_fc2d(
    const float* __restrict__ cur1, const _Float16* __restrict__ W2h,
    const _Float16* __restrict__ W2l, const float* __restrict__ b2p,
    float* __restrict__ outp, float* __restrict__ spars) {
  extern __shared__ char smem[];       // Ah[32][528] + Al[32][528] = 33792
  char* Ah = smem;
  char* Al = smem + 32 * ROWH;
  const int tid = threadIdx.x;
  const int l   = tid & 63;
  const int w   = tid >> 6;            // 0..7 = n-wave
  const int l15 = l & 15, lq = l >> 4;
  const int ct  = blockIdx.x;          // 0..7
  const int mt  = blockIdx.y;          // 0..511
  const int mb  = mt * 32;
  const int cls = ct * 128 + w * 16 + l15;

  // hoist W2 hi/lo fragments for this wave's 16 classes (whole kernel)
  half8 whf[8], wlf[8];
#pragma unroll
  for (int fk = 0; fk < 8; ++fk) {
    whf[fk] = *(const half8*)(W2h + (size_t)cls * HID + (fk * 4 + lq) * 8);
    wlf[fk] = *(const half8*)(W2l + (size_t)cls * HID + (fk * 4 + lq) * 8);
  }
  const float b2v = b2p[cls];

  // this thread's 16 recurrence elements: row r0, h = h0..h0+15
  const int r0 = tid >> 4;             // 0..31
  const int h0 = (tid & 15) * 16;
  f32x4 cr[4], m1[4];
#pragma unroll
  for (int j = 0; j < 4; ++j) {
    cr[j] = *(const float4v*)(cur1 + (size_t)(mb + r0) * HID + h0 + j * 4);
    m1[j] = f32x4{0,0,0,0};
  }

  f32x4 mem2[2], cnt[2];
#pragma unroll
  for (int fm = 0; fm < 2; ++fm) { mem2[fm] = f32x4{0,0,0,0}; cnt[fm] = f32x4{0,0,0,0}; }

  float ssum = 0.0f;

#pragma unroll 1
  for (int t = 0; t < NSTEPS; ++t) {
    // --- layer-1 LIF for this thread's 16 elements; write spk hi/lo to LDS
    half8 sh[2], sl[2];
#pragma unroll
    for (int j = 0; j < 4; ++j) {
      m1[j] = m1[j] * BETA + cr[j];
#pragma unroll
      for (int e = 0; e < 4; ++e) {
        float s = sigmoid10(m1[j][e]);
        m1[j][e] = __builtin_fmaf(-s, m1[j][e], m1[j][e]);
        _Float16 hv = (_Float16)s;
        sh[j >> 1][(j & 1) * 4 + e] = hv;
        sl[j >> 1][(j & 1) * 4 + e] = (_Float16)((s - (float)hv) * SCL);
        if (t == NSTEPS - 1) ssum += s;
      }
    }
    *(half8*)(Ah + r0 * ROWH + h0 * 2)      = sh[0];
    *(half8*)(Ah + r0 * ROWH + h0 * 2 + 16) = sh[1];
    *(half8*)(Al + r0 * ROWH + h0 * 2)      = sl[0];
    *(half8*)(Al + r0 * ROWH + h0 * 2 + 16) = sl[1];
    __syncthreads();

    // --- fc2 tile: 32 x 16(classes) per wave, K=256, 3-term split
    f32x4 am2[2], ac2[2];
#pragma unroll
    for (int fm = 0; fm < 2; ++fm) {
      am2[fm] = mem2[fm] * BETA + b2v;     // leak + bias as C-init
      ac2[fm] = f32x4{0,0,0,0};
    }
#pragma unroll
    for (int fk = 0; fk < 8; ++fk) {
      const int g16 = (fk * 4 + lq) * 16;
      half8 ah[2], al[2];
#pragma unroll
      for (int fm = 0; fm < 2; ++fm) {
        int r = fm * 16 + l15;
        ah[fm] = *(const half8*)(Ah + r * ROWH + g16);
        al[fm] = *(const half8*)(Al + r * ROWH + g16);
      }
#pragma unroll
      for (int fm = 0; fm < 2; ++fm) {
        am2[fm] = __builtin_amdgcn_mfma_f32_16x16x32_f16(ah[fm], whf[fk], am2[fm], 0, 0, 0);
        ac2[fm] = __builtin_amdgcn_mfma_f32_16x16x32_f16(ah[fm], wlf[fk], ac2[fm], 0, 0, 0);
        ac2[fm] = __builtin_amdgcn_mfma_f32_16x16x32_f16(al[fm], whf[fk], ac2[fm], 0, 0, 0);
      }
    }
    // --- layer-2 LIF
#pragma unroll
    for (int fm = 0; fm < 2; ++fm) {
#pragma unroll
      for (int e = 0; e < 4; ++e) {
        float c2 = am2[fm][e] + ac2[fm][e] * ISCL;
        float s2 = sigmoid10(c2);
        mem2[fm][e] = __builtin_fmaf(-s2, c2, c2);
        cnt[fm][e] += s2;
      }
    }
    __syncthreads();
  }

  // --- outputs
#pragma unroll
  for (int fm = 0; fm < 2; ++fm) {
    if (cls < NCLS) {
      int m0 = mb + fm * 16 + lq * 4;
#pragma unroll
      for (int e = 0; e < 4; ++e)
        outp[(size_t)(m0 + e) * NCLS + cls] = cnt[fm][e] * (1.0f / NSTEPS);
    }
  }
  // sparsity (mean of last-step spk1): only ct==0 blocks contribute
  if (ct == 0) {
#pragma unroll
    for (int off = 32; off; off >>= 1) ssum += __shfl_down(ssum, off, 64);
    if (l == 0) atomicAdd(spars, ssum);
  }
}

// ------------- finalize sparsity scalar -------------
__global__ void k_fin(const float* __restrict__ spars, float* __restrict__ outp) {
  if (threadIdx.x == 0 && blockIdx.x == 0)
    outp[(size_t)BATCH * NCLS] = spars[0] * (1.0f / ((float)BATCH * (float)HID));
}

extern "C" void kernel_launch(void* const* d_in, const int* in_sizes, int n_in,
                              void* d_out, int out_size, void* d_ws, size_t ws_size,
                              hipStream_t stream) {
  const float* x  = (const float*)d_in[0];
  const float* W1 = (const float*)d_in[1];
  const float* b1 = (const float*)d_in[2];
  const float* W2 = (const float*)d_in[3];
  const float* b2 = (const float*)d_in[4];
  float* outp = (float*)d_out;
  char* ws = (char*)d_ws;

  float*    cur1 = (float*)(ws + WS_CUR1);
  _Float16* W2h  = (_Float16*)(ws + WS_W2H);
  _Float16* W2l  = (_Float16*)(ws + WS_W2L);
  float*    b2p  = (float*)(ws + WS_B2P);
  float*    spars= (float*)(ws + WS_SPARS);

  (void)in_sizes; (void)n_in; (void)out_size; (void)ws_size;

  // allow >64KB dynamic LDS for k_fc1 (host-side, idempotent, capture-safe)
  static bool attr_set = false;
  if (!attr_set) {
    hipFuncSetAttribute((const void*)k_fc1,
                        hipFuncAttributeMaxDynamicSharedMemorySize, 92160);
    attr_set = true;
  }

  hipMemsetAsync(spars, 0, sizeof(float), stream);
  k_cast_w2<<<dim3(NCLSP), dim3(HID), 0, stream>>>(W2, b2, W2h, W2l, b2p);
  k_fc1<<<dim3(BATCH / 64), dim3(512), 92160, stream>>>(x, W1, b1, cur1);
  k_fc2d<<<dim3(NCLSP / 128, BATCH / 32), dim3(512), 33792, stream>>>(cur1, W2h, W2l, b2p, outp, spars);
  k_fin<<<dim3(1), dim3(64), 0, stream>>>(spars, outp);
}

// Round 6
// 1082.411 us; speedup vs baseline: 1.1305x; 1.1305x over previous
//
#include <hip/hip_runtime.h>
#include <cstdint>
#include <cstddef>

typedef __attribute__((ext_vector_type(4)))  float    f32x4;
typedef __attribute__((ext_vector_type(16))) float    f32x16;
typedef __attribute__((ext_vector_type(4)))  float    float4v;
typedef __attribute__((ext_vector_type(8)))  _Float16 f16x8;
typedef __attribute__((ext_vector_type(4)))  _Float16 half4;
typedef __attribute__((ext_vector_type(8)))  _Float16 half8;

#define BATCH   16384
#define DIN     2048
#define HID     256
#define NCLS    1000
#define NCLSP   1024
#define NSTEPS  25
#define BETA    0.9f
#define SGK     14.4269504089f   /* 10 * log2(e) */
#define SCL     4096.0f          /* 2^12 lo-scale */
#define ISCL    (1.0f/4096.0f)

// ---- ws layout (bytes); total ~17.8MB ----
#define WS_CUR1   0                       // 16384*256*4 = 16,777,216
#define WS_W2H    16777216                // 1024*256*2  = 524,288
#define WS_W2L    17301504                // 524,288
#define WS_B2P    17825792                // 4096
#define WS_SPARS  17829888                // 4

__device__ __forceinline__ float sigmoid10(float m) {
  // sigmoid(10*(m-1)) = 1/(1+exp2(-10*log2e*(m-1)))
  float z = __builtin_fmaf(-SGK, m, SGK);
  float e = __builtin_amdgcn_exp2f(z);
  return __builtin_amdgcn_rcpf(1.0f + e);
}

// ------------- cast W2/b2 -> f16 hi + scaled-lo (padded to 1024 rows) -------
__global__ void k_cast_w2(const float* __restrict__ W2, const float* __restrict__ b2,
                          _Float16* __restrict__ W2h, _Float16* __restrict__ W2l,
                          float* __restrict__ b2p) {
  int row = blockIdx.x;          // 0..1023
  int t   = threadIdx.x;         // 0..255
  float v = (row < NCLS) ? W2[(size_t)row * HID + t] : 0.0f;
  _Float16 h = (_Float16)v;
  _Float16 l = (_Float16)((v - (float)h) * SCL);
  W2h[(size_t)row * HID + t] = h;
  W2l[(size_t)row * HID + t] = l;
  if (t == 0) b2p[row] = (row < NCLS) ? b2[row] : 0.0f;
}

// ------------- fc1: cur1 = x @ W1^T + b1, f16 2-way split, 3-term MFMA ------
#define ROWB1 144    // 64 f16 (128B) + 16B pad
__global__ __launch_bounds__(512) void k_fc1(
    const float* __restrict__ x, const float* __restrict__ W1,
    const float* __restrict__ b1, float* __restrict__ cur1) {
  extern __shared__ char smem[];
  char* xh = smem;                    // 64*144  = 9216
  char* xl = smem + 9216;             // 9216
  char* wh = smem + 18432;            // 256*144 = 36864
  char* wl = smem + 55296;            // 36864 -> 92160 total
  const int tid = threadIdx.x;
  const int l   = tid & 63;
  const int w   = tid >> 6;
  const int wm  = w >> 2;             // 0..1
  const int wn  = w & 3;              // 0..3
  const int l15 = l & 15, lq = l >> 4;
  const int mbase = blockIdx.x * 64;

  f32x4 am[2][4], ac[2][4];
#pragma unroll
  for (int i = 0; i < 2; ++i)
#pragma unroll
    for (int j = 0; j < 4; ++j) { am[i][j] = f32x4{0,0,0,0}; ac[i][j] = f32x4{0,0,0,0}; }

  const int srow = tid >> 4;          // 0..31
  const int c4   = (tid & 15) * 4;

#pragma unroll 1
  for (int kt = 0; kt < DIN / 64; ++kt) {
    const int k0 = kt * 64;
#pragma unroll
    for (int j = 0; j < 2; ++j) {      // x tile [64][64]
      int r = j * 32 + srow;
      float4v v = *(const float4v*)(x + (size_t)(mbase + r) * DIN + k0 + c4);
      half4 h, lo;
#pragma unroll
      for (int e = 0; e < 4; ++e) {
        _Float16 hv = (_Float16)v[e];
        h[e]  = hv;
        lo[e] = (_Float16)((v[e] - (float)hv) * SCL);
      }
      *(half4*)(xh + r * ROWB1 + (tid & 15) * 8) = h;
      *(half4*)(xl + r * ROWB1 + (tid & 15) * 8) = lo;
    }
#pragma unroll
    for (int j = 0; j < 8; ++j) {      // W1 tile [256][64]
      int r = j * 32 + srow;
      float4v v = *(const float4v*)(W1 + (size_t)r * DIN + k0 + c4);
      half4 h, lo;
#pragma unroll
      for (int e = 0; e < 4; ++e) {
        _Float16 hv = (_Float16)v[e];
        h[e]  = hv;
        lo[e] = (_Float16)((v[e] - (float)hv) * SCL);
      }
      *(half4*)(wh + r * ROWB1 + (tid & 15) * 8) = h;
      *(half4*)(wl + r * ROWB1 + (tid & 15) * 8) = lo;
    }
    __syncthreads();
#pragma unroll
    for (int fk = 0; fk < 2; ++fk) {
      const int g16 = (fk * 4 + lq) * 16;
      half8 ah[2], al[2], bh[4], bl[4];
#pragma unroll
      for (int fm = 0; fm < 2; ++fm) {
        int r = wm * 32 + fm * 16 + l15;
        ah[fm] = *(const half8*)(xh + r * ROWB1 + g16);
        al[fm] = *(const half8*)(xl + r * ROWB1 + g16);
      }
#pragma unroll
      for (int fn = 0; fn < 4; ++fn) {
        int r = wn * 64 + fn * 16 + l15;
        bh[fn] = *(const half8*)(wh + r * ROWB1 + g16);
        bl[fn] = *(const half8*)(wl + r * ROWB1 + g16);
      }
#pragma unroll
      for (int fm = 0; fm < 2; ++fm)
#pragma unroll
        for (int fn = 0; fn < 4; ++fn) {
          am[fm][fn] = __builtin_amdgcn_mfma_f32_16x16x32_f16(ah[fm], bh[fn], am[fm][fn], 0, 0, 0);
          ac[fm][fn] = __builtin_amdgcn_mfma_f32_16x16x32_f16(ah[fm], bl[fn], ac[fm][fn], 0, 0, 0);
          ac[fm][fn] = __builtin_amdgcn_mfma_f32_16x16x32_f16(al[fm], bh[fn], ac[fm][fn], 0, 0, 0);
        }
    }
    __syncthreads();
  }
#pragma unroll
  for (int fn = 0; fn < 4; ++fn) {
    int h = wn * 64 + fn * 16 + l15;
    float b1v = b1[h];
#pragma unroll
    for (int fm = 0; fm < 2; ++fm) {
      int m0 = mbase + wm * 32 + fm * 16 + lq * 4;
#pragma unroll
      for (int e = 0; e < 4; ++e)
        cur1[(size_t)(m0 + e) * HID + h] = am[fm][fn][e] + ac[fm][fn][e] * ISCL + b1v;
    }
  }
}

// ------------- fc2 + both LIF dynamics, pipelined 32x32 MFMA version --------
// block: 32 batch rows x 256 classes; 512 thr = 8 waves, each wave 32x32 tile.
// 3-term f16-split via mfma_f32_32x32x16_f16; double-buffered swizzled spk LDS;
// ONE barrier per step; recurrence(t+1) overlaps MFMA(t).
// LDS: buf0 Ah[0,16K) Al[16K,32K); buf1 [32K,64K); cr [64K, +33280); cnt [.., +40960)
#define LDS_CR   65536
#define LDS_CNT  98816
#define LDS_TOT  139776
__global__ __launch_bounds__(512, 2) void k_fc2d(
    const float* __restrict__ cur1, const _Float16* __restrict__ W2h,
    const _Float16* __restrict__ W2l, const float* __restrict__ b2p,
    float* __restrict__ outp, float* __restrict__ spars) {
  extern __shared__ char smem[];
  char* crb  = smem + LDS_CR;
  char* cntb = smem + LDS_CNT;
  const int tid = threadIdx.x;
  const int l   = tid & 63;
  const int w   = tid >> 6;        // 0..7
  const int l31 = l & 31;
  const int hi  = l >> 5;          // 0..1
  const int ct  = blockIdx.x;      // 0..3
  const int mt  = blockIdx.y;      // 0..511
  const int mb  = mt * 32;
  const int cls = ct * 256 + w * 32 + l31;

  // W2 hi/lo fragments, register-resident for the whole kernel (128 VGPR)
  f16x8 whf[16], wlf[16];
#pragma unroll
  for (int k = 0; k < 16; ++k) {
    size_t o = (size_t)cls * HID + k * 16 + hi * 8;
    whf[k] = *(const f16x8*)(W2h + o);
    wlf[k] = *(const f16x8*)(W2l + o);
  }
  const float b2v = b2p[cls];

  // recurrence ownership: row r0, cols h0..h0+15
  const int r0  = tid >> 4;        // 0..31
  const int c15 = tid & 15;
  const int h0  = c15 * 16;

  // load cr from global; stash in LDS (regs freed after prologue)
  f32x4 cr0[4];
#pragma unroll
  for (int j = 0; j < 4; ++j) {
    cr0[j] = *(const float4v*)(cur1 + (size_t)(mb + r0) * HID + h0 + j * 4);
    *(f32x4*)(crb + r0 * 1040 + c15 * 64 + j * 16) = cr0[j];
  }
  // zero cnt accumulator (LDS, per-thread 16 f32, stride 80)
#pragma unroll
  for (int j = 0; j < 4; ++j)
    *(f32x4*)(cntb + tid * 80 + j * 16) = f32x4{0,0,0,0};

  // swizzled write addresses for spk tiles: slot = (c16 + 2*row) & 31
  const int cb  = c15 * 2;
  const int wb0 = r0 * 512 + (((cb     + 2 * r0) & 31) << 4);
  const int wb1 = r0 * 512 + (((cb + 1 + 2 * r0) & 31) << 4);

  f32x4 m1[4];
#pragma unroll
  for (int j = 0; j < 4; ++j) m1[j] = f32x4{0,0,0,0};
  float ssum = 0.0f;

  // ---- prologue: rec(0) from registers -> buf0
  {
    f16x8 sh[2], sl[2];
#pragma unroll
    for (int j = 0; j < 4; ++j) {
      m1[j] = m1[j] * BETA + cr0[j];
#pragma unroll
      for (int e = 0; e < 4; ++e) {
        float s = sigmoid10(m1[j][e]);
        m1[j][e] = __builtin_fmaf(-s, m1[j][e], m1[j][e]);
        _Float16 hv = (_Float16)s;
        sh[j >> 1][(j & 1) * 4 + e] = hv;
        sl[j >> 1][(j & 1) * 4 + e] = (_Float16)((s - (float)hv) * SCL);
      }
    }
    *(f16x8*)(smem + wb0)         = sh[0];
    *(f16x8*)(smem + wb1)         = sh[1];
    *(f16x8*)(smem + 16384 + wb0) = sl[0];
    *(f16x8*)(smem + 16384 + wb1) = sl[1];
  }
  __syncthreads();

  f32x16 mem2;
#pragma unroll
  for (int e = 0; e < 16; ++e) mem2[e] = 0.0f;

  const int arow = l31 * 512;

#pragma unroll 1
  for (int t = 0; t < NSTEPS; ++t) {
    char* bufc = smem + ((t & 1) << 15);
    char* bufn = smem + (((t + 1) & 1) << 15);

    f32x16 am, ac;
#pragma unroll
    for (int e = 0; e < 16; ++e) { am[e] = __builtin_fmaf(BETA, mem2[e], b2v); ac[e] = 0.0f; }

    // MFMA over K=256: 16 k-iters x 3 terms, operands from swizzled LDS (2-way free)
#pragma unroll
    for (int k = 0; k < 16; ++k) {
      int ad = arow + (((2 * k + hi + 2 * l31) & 31) << 4);
      f16x8 ah = *(const f16x8*)(bufc + ad);
      f16x8 al = *(const f16x8*)(bufc + 16384 + ad);
      am = __builtin_amdgcn_mfma_f32_32x32x16_f16(ah, whf[k], am, 0, 0, 0);
      ac = __builtin_amdgcn_mfma_f32_32x32x16_f16(ah, wlf[k], ac, 0, 0, 0);
      ac = __builtin_amdgcn_mfma_f32_32x32x16_f16(al, whf[k], ac, 0, 0, 0);
    }

    // recurrence for t+1 (independent of MFMA above -> overlaps on VALU pipe)
    if (t < NSTEPS - 1) {
      f16x8 sh[2], sl[2];
#pragma unroll
      for (int j = 0; j < 4; ++j) {
        f32x4 c = *(const f32x4*)(crb + r0 * 1040 + c15 * 64 + j * 16);
        m1[j] = m1[j] * BETA + c;
#pragma unroll
        for (int e = 0; e < 4; ++e) {
          float s = sigmoid10(m1[j][e]);
          m1[j][e] = __builtin_fmaf(-s, m1[j][e], m1[j][e]);
          _Float16 hv = (_Float16)s;
          sh[j >> 1][(j & 1) * 4 + e] = hv;
          sl[j >> 1][(j & 1) * 4 + e] = (_Float16)((s - (float)hv) * SCL);
          if (t + 1 == NSTEPS - 1) ssum += s;
        }
      }
      *(f16x8*)(bufn + wb0)         = sh[0];
      *(f16x8*)(bufn + wb1)         = sh[1];
      *(f16x8*)(bufn + 16384 + wb0) = sl[0];
      *(f16x8*)(bufn + 16384 + wb1) = sl[1];
    }

    // layer-2 LIF + spike-count accumulation (cnt in LDS)
#pragma unroll
    for (int j = 0; j < 4; ++j) {
      f32x4 cn = *(const f32x4*)(cntb + tid * 80 + j * 16);
#pragma unroll
      for (int e = 0; e < 4; ++e) {
        int q = j * 4 + e;
        float c2 = __builtin_fmaf(ac[q], ISCL, am[q]);
        float s2 = sigmoid10(c2);
        mem2[q] = __builtin_fmaf(-s2, c2, c2);
        cn[e] += s2;
      }
      *(f32x4*)(cntb + tid * 80 + j * 16) = cn;
    }
    __syncthreads();
  }

  // ---- outputs: C/D layout col=l&31, row=(reg&3)+8*(reg>>2)+4*(l>>5)
  if (cls < NCLS) {
#pragma unroll
    for (int j = 0; j < 4; ++j) {
      f32x4 cn = *(const f32x4*)(cntb + tid * 80 + j * 16);
#pragma unroll
      for (int e = 0; e < 4; ++e) {
        int q = j * 4 + e;
        int rloc = (q & 3) + 8 * (q >> 2) + 4 * hi;
        outp[(size_t)(mb + rloc) * NCLS + cls] = cn[e] * (1.0f / NSTEPS);
      }
    }
  }
  // sparsity (mean of last-step spk1): only ct==0 blocks contribute
  if (ct == 0) {
#pragma unroll
    for (int off = 32; off; off >>= 1) ssum += __shfl_down(ssum, off, 64);
    if (l == 0) atomicAdd(spars, ssum);
  }
}

// ------------- finalize sparsity scalar -------------
__global__ void k_fin(const float* __restrict__ spars, float* __restrict__ outp) {
  if (threadIdx.x == 0 && blockIdx.x == 0)
    outp[(size_t)BATCH * NCLS] = spars[0] * (1.0f / ((float)BATCH * (float)HID));
}

extern "C" void kernel_launch(void* const* d_in, const int* in_sizes, int n_in,
                              void* d_out, int out_size, void* d_ws, size_t ws_size,
                              hipStream_t stream) {
  const float* x  = (const float*)d_in[0];
  const float* W1 = (const float*)d_in[1];
  const float* b1 = (const float*)d_in[2];
  const float* W2 = (const float*)d_in[3];
  const float* b2 = (const float*)d_in[4];
  float* outp = (float*)d_out;
  char* ws = (char*)d_ws;

  float*    cur1 = (float*)(ws + WS_CUR1);
  _Float16* W2h  = (_Float16*)(ws + WS_W2H);
  _Float16* W2l  = (_Float16*)(ws + WS_W2L);
  float*    b2p  = (float*)(ws + WS_B2P);
  float*    spars= (float*)(ws + WS_SPARS);

  (void)in_sizes; (void)n_in; (void)out_size; (void)ws_size;

  // allow >64KB dynamic LDS (host-side, idempotent, capture-safe)
  hipFuncSetAttribute((const void*)k_fc1,
                      hipFuncAttributeMaxDynamicSharedMemorySize, 92160);
  hipFuncSetAttribute((const void*)k_fc2d,
                      hipFuncAttributeMaxDynamicSharedMemorySize, LDS_TOT);

  hipMemsetAsync(spars, 0, sizeof(float), stream);
  k_cast_w2<<<dim3(NCLSP), dim3(HID), 0, stream>>>(W2, b2, W2h, W2l, b2p);
  k_fc1<<<dim3(BATCH / 64), dim3(512), 92160, stream>>>(x, W1, b1, cur1);
  k_fc2d<<<dim3(NCLSP / 256, BATCH / 32), dim3(512), LDS_TOT, stream>>>(cur1, W2h, W2l, b2p, outp, spars);
  k_fin<<<dim3(1), dim3(64), 0, stream>>>(spars, outp);
}